// Round 1
// baseline (624.315 us; speedup 1.0000x reference)
//
#include <hip/hip_runtime.h>
#include <cstdint>

#define KNB 16
#define FDIM 64
#define HDIM 128

typedef unsigned long long ull;

__device__ __forceinline__ ull pack_key(float d, int j){
    return (((ull)__float_as_uint(d)) << 32) | (unsigned int)j;
}

__device__ __forceinline__ float selu_f(float x){
    const float a = 1.6732632423543772f, s = 1.0507009873554805f;
    return x > 0.f ? s * x : s * a * expm1f(x);
}

// ---------------------------------------------------------------------------
// Kernel 1: exact KNN per point. One block (256 threads) per point.
// Replicates reference: d2 = nrm_i + nrm_j - 2*dot, clamp 0, top-(K+1)
// ascending by (d2, j) — stable tie-break by index, self included.
// ---------------------------------------------------------------------------
__global__ __launch_bounds__(256) void knn_kernel(
    const float* __restrict__ coords,
    const int* __restrict__ row_splits, int nseg, int n,
    int* __restrict__ nidx, float* __restrict__ ndist, int* __restrict__ idx0,
    float* __restrict__ out_nidx, float* __restrict__ out_d)
{
    const int i   = blockIdx.x;
    const int tid = threadIdx.x;

    int lo = 0, hi = n;
    for (int s = 0; s < nseg; ++s){
        int a = row_splits[s], b = row_splits[s+1];
        if (i >= a && i < b){ lo = a; hi = b; }
    }

    const float cx = coords[3*i], cy = coords[3*i+1], cz = coords[3*i+2];
    const float nrmi = __fadd_rn(__fadd_rn(__fmul_rn(cx,cx), __fmul_rn(cy,cy)), __fmul_rn(cz,cz));

    // per-thread candidates, fully unrolled (static register indexing)
    const int CMAX = 20;   // covers segments up to 5120 points (here: 5000)
    ull key[CMAX];
    #pragma unroll
    for (int c = 0; c < CMAX; ++c){
        int j = lo + tid + c*256;
        ull kk = ~0ull;
        if (j < hi){
            float x = coords[3*j], y = coords[3*j+1], z = coords[3*j+2];
            float nrmj = __fadd_rn(__fadd_rn(__fmul_rn(x,x), __fmul_rn(y,y)), __fmul_rn(z,z));
            float dot  = __fadd_rn(__fadd_rn(__fmul_rn(cx,x), __fmul_rn(cy,y)), __fmul_rn(cz,z));
            float d2 = __fsub_rn(__fadd_rn(nrmi, nrmj), __fmul_rn(2.0f, dot));
            d2 = fmaxf(d2, 0.0f);
            kk = pack_key(d2, j);
        }
        key[c] = kk;
    }

    __shared__ ull wmin[4];
    __shared__ ull sbest;
    __shared__ int   outj[KNB+1];
    __shared__ float outd[KNB+1];
    const int lane = tid & 63, wid = tid >> 6;

    for (int r = 0; r < KNB+1; ++r){
        ull m = ~0ull;
        #pragma unroll
        for (int c = 0; c < CMAX; ++c) m = key[c] < m ? key[c] : m;
        #pragma unroll
        for (int off = 32; off > 0; off >>= 1){
            ull o = __shfl_down(m, off, 64);
            m = o < m ? o : m;
        }
        if (lane == 0) wmin[wid] = m;
        __syncthreads();
        if (tid == 0){
            ull b = wmin[0];
            b = wmin[1] < b ? wmin[1] : b;
            b = wmin[2] < b ? wmin[2] : b;
            b = wmin[3] < b ? wmin[3] : b;
            sbest = b;
            outj[r] = (int)(b & 0xffffffffull);
            outd[r] = __uint_as_float((unsigned int)(b >> 32));
        }
        __syncthreads();
        ull b = sbest;
        #pragma unroll
        for (int c = 0; c < CMAX; ++c) if (key[c] == b) key[c] = ~0ull;
        __syncthreads();
    }

    if (tid == 0) idx0[i] = outj[0];
    if (tid >= 1 && tid <= KNB){
        int r = tid - 1;
        int j = outj[tid];
        float d = outd[tid];
        nidx[i*KNB + r]    = j;
        ndist[i*KNB + r]   = d;
        out_nidx[i*KNB + r] = (float)j;
        out_d[i*KNB + r]    = d;
    }
}

// ---------------------------------------------------------------------------
// Dense 128->128 layer helper for the edge MLP.
// Thread mapping: og = tid&63 handles outputs {og, og+64}; kq = tid>>6 handles
// edges {4kq..4kq+3}. Inner loop blocked by 4 inputs: 8 coalesced W loads +
// 4 ds_read_b128 broadcasts feed 32 FMAs.
// ---------------------------------------------------------------------------
__device__ __forceinline__ void dense_layer(
    const float* __restrict__ W,       // rows x 128, starting at inner-input row
    const float* __restrict__ bias,
    const float* __restrict__ inb,     // LDS: [16][128]
    float* __restrict__ outb,          // LDS: [16][128]
    const float* __restrict__ init,    // per-k extra input value (radial) or nullptr
    const float* __restrict__ Wrow0,   // W row for the radial input (e1) or nullptr
    int tid, bool act)
{
    const int og = tid & 63;
    const int kq = tid >> 6;
    const int o0 = og, o1 = og + 64;

    float acc[2][4];
    const float bz0 = bias[o0], bz1 = bias[o1];
    float wr0 = 0.f, wr1 = 0.f;
    if (init){ wr0 = Wrow0[o0]; wr1 = Wrow0[o1]; }
    #pragma unroll
    for (int m = 0; m < 4; ++m){
        float a0 = bz0, a1 = bz1;
        if (init){
            float dv = init[kq*4 + m];
            a0 = fmaf(dv, wr0, a0);
            a1 = fmaf(dv, wr1, a1);
        }
        acc[0][m] = a0; acc[1][m] = a1;
    }

    for (int in0 = 0; in0 < 128; in0 += 4){
        const float* Wp = W + (size_t)in0 * 128;
        float w00 = Wp[o0],        w01 = Wp[128 + o0];
        float w02 = Wp[256 + o0],  w03 = Wp[384 + o0];
        float w10 = Wp[o1],        w11 = Wp[128 + o1];
        float w12 = Wp[256 + o1],  w13 = Wp[384 + o1];
        #pragma unroll
        for (int m = 0; m < 4; ++m){
            const float4 e = *(const float4*)&inb[(kq*4 + m)*HDIM + in0];
            acc[0][m] = fmaf(e.x, w00, acc[0][m]);
            acc[0][m] = fmaf(e.y, w01, acc[0][m]);
            acc[0][m] = fmaf(e.z, w02, acc[0][m]);
            acc[0][m] = fmaf(e.w, w03, acc[0][m]);
            acc[1][m] = fmaf(e.x, w10, acc[1][m]);
            acc[1][m] = fmaf(e.y, w11, acc[1][m]);
            acc[1][m] = fmaf(e.z, w12, acc[1][m]);
            acc[1][m] = fmaf(e.w, w13, acc[1][m]);
        }
    }

    #pragma unroll
    for (int m = 0; m < 4; ++m){
        int k = kq*4 + m;
        float v0 = acc[0][m], v1 = acc[1][m];
        if (act){ v0 = selu_f(v0); v1 = selu_f(v1); }
        outb[k*HDIM + o0] = v0;
        outb[k*HDIM + o1] = v1;
    }
}

// ---------------------------------------------------------------------------
// Kernel 2: per-node fused edge MLP + coord update + node MLP.
// One block (256 threads) per node; its 16 edges are processed together so
// e_sum needs no atomics.
// ---------------------------------------------------------------------------
__global__ __launch_bounds__(256) void egcn_node_kernel(
    const float* __restrict__ h, const float* __restrict__ coords,
    const int* __restrict__ nidx, const float* __restrict__ ndist,
    const int* __restrict__ idx0,
    const float* __restrict__ W_e1, const float* __restrict__ b_e1,
    const float* __restrict__ W_e2, const float* __restrict__ b_e2,
    const float* __restrict__ W_c1, const float* __restrict__ b_c1,
    const float* __restrict__ W_c2, const float* __restrict__ b_c2,
    const float* __restrict__ W_n1, const float* __restrict__ b_n1,
    const float* __restrict__ W_n2, const float* __restrict__ b_n2,
    float* __restrict__ out, float* __restrict__ out_coords)
{
    __shared__ __attribute__((aligned(16))) float ein [KNB][HDIM]; // [h_self|h_nbr]
    __shared__ __attribute__((aligned(16))) float bufA[KNB][HDIM];
    __shared__ __attribute__((aligned(16))) float bufB[KNB][HDIM];
    __shared__ float dloc[KNB];
    __shared__ int   nb[KNB];
    __shared__ float wgt[KNB];
    __shared__ float agg[HDIM + FDIM];
    __shared__ float an[HDIM];
    __shared__ float part[256];

    const int i   = blockIdx.x;
    const int tid = threadIdx.x;

    if (tid < KNB){
        nb[tid]   = nidx[i*KNB + tid];
        dloc[tid] = ndist[i*KNB + tid];
    }
    __syncthreads();

    const int j0 = idx0[i];
    if (tid < FDIM){
        float v = h[(size_t)j0*FDIM + tid];
        #pragma unroll
        for (int k = 0; k < KNB; ++k) ein[k][tid] = v;
    }
    for (int s = tid; s < KNB*FDIM; s += 256){
        int k = s >> 6, f = s & 63;
        ein[k][FDIM + f] = h[(size_t)nb[k]*FDIM + f];
    }
    __syncthreads();

    // e1: 129 -> 128 (row 0 = radial, rows 1..128 = [h_self|h_nbr])
    dense_layer(W_e1 + HDIM, b_e1, &ein[0][0], &bufA[0][0], dloc, W_e1, tid, true);
    __syncthreads();
    // e2: 128 -> 128  (bufB = e)
    dense_layer(W_e2, b_e2, &bufA[0][0], &bufB[0][0], nullptr, nullptr, tid, true);
    __syncthreads();
    // c1: 128 -> 128  (bufA = c)
    dense_layer(W_c1, b_c1, &bufB[0][0], &bufA[0][0], nullptr, nullptr, tid, true);
    __syncthreads();

    // c2: w[k] = b_c2 + sum_o c[k][o]*W_c2[o]
    {
        int k = tid >> 4, os = tid & 15;
        float p = 0.f;
        #pragma unroll
        for (int m = 0; m < 8; ++m){
            int o = os + m*16;
            p = fmaf(bufA[k][o], W_c2[o], p);
        }
        part[tid] = p;
    }
    __syncthreads();
    if (tid < KNB){
        float s = b_c2[0];
        #pragma unroll
        for (int m = 0; m < 16; ++m) s += part[tid*16 + m];
        wgt[tid] = s;
    }
    __syncthreads();

    // e_sum -> agg[0..127], h_self -> agg[128..191], coords update
    if (tid < HDIM){
        float s = 0.f;
        #pragma unroll
        for (int k = 0; k < KNB; ++k) s += bufB[k][tid];
        agg[tid] = s;
    } else if (tid < HDIM + FDIM){
        agg[tid] = ein[0][tid - HDIM];
    } else if (tid < HDIM + FDIM + 3){
        int c = tid - (HDIM + FDIM);
        float ci = coords[3*i + c];
        float s = 0.f;
        #pragma unroll
        for (int k = 0; k < KNB; ++k) s += (ci - coords[3*nb[k] + c]) * wgt[k];
        out_coords[3*i + c] = ci + s * (1.0f/KNB);
    }
    __syncthreads();

    // node layer 1: 192 -> 128 (split input range across the two halves)
    {
        int o = tid & 127, half = tid >> 7;
        float acc = (half == 0) ? b_n1[o] : 0.f;
        int inlo = half * 96;
        for (int in = inlo; in < inlo + 96; ++in)
            acc = fmaf(agg[in], W_n1[(size_t)in*HDIM + o], acc);
        part[tid] = acc;
    }
    __syncthreads();
    if (tid < HDIM) an[tid] = selu_f(part[tid] + part[tid + 128]);
    __syncthreads();

    // node layer 2: 128 -> 128 (no activation)
    {
        int o = tid & 127, half = tid >> 7;
        float acc = (half == 0) ? b_n2[o] : 0.f;
        int inlo = half * 64;
        for (int in = inlo; in < inlo + 64; ++in)
            acc = fmaf(an[in], W_n2[(size_t)in*HDIM + o], acc);
        part[tid] = acc;
    }
    __syncthreads();
    if (tid < HDIM) out[(size_t)i*HDIM + tid] = part[tid] + part[tid + 128];
}

extern "C" void kernel_launch(void* const* d_in, const int* in_sizes, int n_in,
                              void* d_out, int out_size, void* d_ws, size_t ws_size,
                              hipStream_t stream)
{
    const float* h          = (const float*)d_in[0];
    const float* coords     = (const float*)d_in[1];
    const int*   row_splits = (const int*)  d_in[2];
    const float* W_e1 = (const float*)d_in[3];
    const float* b_e1 = (const float*)d_in[4];
    const float* W_e2 = (const float*)d_in[5];
    const float* b_e2 = (const float*)d_in[6];
    const float* W_c1 = (const float*)d_in[7];
    const float* b_c1 = (const float*)d_in[8];
    const float* W_c2 = (const float*)d_in[9];
    const float* b_c2 = (const float*)d_in[10];
    const float* W_n1 = (const float*)d_in[11];
    const float* b_n1 = (const float*)d_in[12];
    const float* W_n2 = (const float*)d_in[13];
    const float* b_n2 = (const float*)d_in[14];

    const int n    = in_sizes[0] / FDIM;
    const int nseg = in_sizes[2] - 1;

    float* out        = (float*)d_out;
    float* out_coords = out + (size_t)n * HDIM;
    float* out_nidx   = out_coords + (size_t)n * 3;
    float* out_d      = out_nidx + (size_t)n * KNB;

    int*   nidx_i = (int*)d_ws;
    float* ndist  = (float*)(nidx_i + (size_t)n * KNB);
    int*   idx0   = (int*)(ndist + (size_t)n * KNB);

    knn_kernel<<<n, 256, 0, stream>>>(coords, row_splits, nseg, n,
                                      nidx_i, ndist, idx0, out_nidx, out_d);

    egcn_node_kernel<<<n, 256, 0, stream>>>(h, coords, nidx_i, ndist, idx0,
                                            W_e1, b_e1, W_e2, b_e2,
                                            W_c1, b_c1, W_c2, b_c2,
                                            W_n1, b_n1, W_n2, b_n2,
                                            out, out_coords);
}

// Round 2
// 317.629 us; speedup vs baseline: 1.9655x; 1.9655x over previous
//
#include <hip/hip_runtime.h>
#include <cstdint>

#define KNB 16
#define FDIM 64
#define HDIM 128
#define SA 130          // Act row stride in f16 units (65 dwords -> conflict-free)
#define SW 65           // WT row stride in dwords

typedef unsigned long long ull;
typedef _Float16 f16x8 __attribute__((ext_vector_type(8)));
typedef float    f32x16 __attribute__((ext_vector_type(16)));

__device__ __forceinline__ ull pack_key(float d, int j){
    return (((ull)__float_as_uint(d)) << 32) | (unsigned int)j;
}

__device__ __forceinline__ float selu_f(float x){
    const float a = 1.6732632423543772f, s = 1.0507009873554805f;
    return x > 0.f ? s * x : s * a * expm1f(x);
}

__device__ __forceinline__ unsigned int pack2(float a, float b){
    union { _Float16 h[2]; unsigned int u; } t;
    t.h[0] = (_Float16)a; t.h[1] = (_Float16)b;
    return t.u;
}

__device__ __forceinline__ f16x8 ldfrag(const unsigned int* p, unsigned int di){
    union { unsigned int u[4]; f16x8 v; } t;
    t.u[0] = p[di]; t.u[1] = p[di+1]; t.u[2] = p[di+2]; t.u[3] = p[di+3];
    return t.v;
}

// ---------------------------------------------------------------------------
// Kernel 0: weights -> transposed fp16 (WT[n][k] = W[k][n]).
// W_e1 skips its radial row 0 (handled in fp32 at acc-init).
// ---------------------------------------------------------------------------
__global__ __launch_bounds__(256) void conv_kernel(
    const float* __restrict__ We1, const float* __restrict__ We2,
    const float* __restrict__ Wc1, _Float16* __restrict__ WT)
{
    int id = blockIdx.x * 256 + threadIdx.x;     // 0..49151
    int m  = id >> 14;
    int r  = id & 16383;
    int nn = (r >> 7) & 127;
    int k  = r & 127;                             // lane varies k -> coalesced writes
    float v;
    if (m == 0)      v = We1[(k + 1) * 128 + nn];
    else if (m == 1) v = We2[k * 128 + nn];
    else             v = Wc1[k * 128 + nn];
    WT[m * 16384 + nn * 128 + k] = (_Float16)v;
}

// ---------------------------------------------------------------------------
// Kernel 1: exact KNN, one 256-thread block per point. Incremental local-min:
// per round only the owner of the extracted key rescans its 20 candidates.
// ---------------------------------------------------------------------------
__global__ __launch_bounds__(256) void knn_kernel(
    const float* __restrict__ coords,
    const int* __restrict__ row_splits, int nseg, int n,
    int* __restrict__ nidx, float* __restrict__ ndist, int* __restrict__ idx0,
    float* __restrict__ out_nidx, float* __restrict__ out_d)
{
    const int i   = blockIdx.x;
    const int tid = threadIdx.x;
    const int lane = tid & 63, wid = tid >> 6;

    int lo = 0, hi = n;
    for (int s = 0; s < nseg; ++s){
        int a = row_splits[s], b = row_splits[s+1];
        if (i >= a && i < b){ lo = a; hi = b; }
    }

    const float cx = coords[3*i], cy = coords[3*i+1], cz = coords[3*i+2];
    const float nrmi = __fadd_rn(__fadd_rn(__fmul_rn(cx,cx), __fmul_rn(cy,cy)), __fmul_rn(cz,cz));

    const int CMAX = 20;   // segments up to 5120 points (here: 5000)
    ull key[CMAX];
    #pragma unroll
    for (int c = 0; c < CMAX; ++c){
        int j = lo + tid + c*256;
        ull kk = ~0ull;
        if (j < hi){
            float x = coords[3*j], y = coords[3*j+1], z = coords[3*j+2];
            float nrmj = __fadd_rn(__fadd_rn(__fmul_rn(x,x), __fmul_rn(y,y)), __fmul_rn(z,z));
            float dot  = __fadd_rn(__fadd_rn(__fmul_rn(cx,x), __fmul_rn(cy,y)), __fmul_rn(cz,z));
            float d2 = __fsub_rn(__fadd_rn(nrmi, nrmj), __fmul_rn(2.0f, dot));
            d2 = fmaxf(d2, 0.0f);
            kk = pack_key(d2, j);
        }
        key[c] = kk;
    }

    __shared__ ull  wminbuf[2][4];
    __shared__ int   outj[KNB+1];
    __shared__ float outd[KNB+1];

    ull m = ~0ull;
    #pragma unroll
    for (int c = 0; c < CMAX; ++c) m = key[c] < m ? key[c] : m;

    for (int r = 0; r < KNB+1; ++r){
        ull wm = m;
        #pragma unroll
        for (int off = 32; off > 0; off >>= 1){
            ull o = __shfl_down(wm, off, 64);
            wm = o < wm ? o : wm;
        }
        if (lane == 0) wminbuf[r&1][wid] = wm;
        __syncthreads();
        ull b = wminbuf[r&1][0];
        ull t = wminbuf[r&1][1]; b = t < b ? t : b;
        t     = wminbuf[r&1][2]; b = t < b ? t : b;
        t     = wminbuf[r&1][3]; b = t < b ? t : b;
        if (tid == 0){
            outj[r] = (int)(b & 0xffffffffull);
            outd[r] = __uint_as_float((unsigned int)(b >> 32));
        }
        if (m == b){   // unique owner: remove + recompute local min
            #pragma unroll
            for (int c = 0; c < CMAX; ++c) if (key[c] == b) key[c] = ~0ull;
            m = ~0ull;
            #pragma unroll
            for (int c = 0; c < CMAX; ++c) m = key[c] < m ? key[c] : m;
        }
        // no trailing barrier: next round writes the other wminbuf slot
    }
    __syncthreads();

    if (tid == 0) idx0[i] = outj[0];
    if (tid >= 1 && tid <= KNB){
        int r = tid - 1;
        nidx[i*KNB + r]     = outj[tid];
        ndist[i*KNB + r]    = outd[tid];
        out_nidx[i*KNB + r] = (float)outj[tid];
        out_d[i*KNB + r]    = outd[tid];
    }
}

// ---------------------------------------------------------------------------
// Kernel 2: 4 nodes (64 edges) per 256-thread block.
// Edge MLP (e1,e2,c1) as f16 MFMA 32x32x16 GEMMs, fp32 accum; c2/e_sum fused
// into epilogues from the fp32 accumulators; node MLP in fp32 vector ALU.
// LDS: Act 16640 + U 33280 + misc ~3.3K = 53.2KB -> 3 blocks/CU.
// ---------------------------------------------------------------------------
__global__ __launch_bounds__(256, 3) void egcn_node_kernel(
    const float* __restrict__ h, const float* __restrict__ coords,
    const int* __restrict__ nidx, const float* __restrict__ ndist,
    const int* __restrict__ idx0, const _Float16* __restrict__ WTg,
    const float* __restrict__ W_e1, const float* __restrict__ b_e1,
    const float* __restrict__ b_e2, const float* __restrict__ b_c1,
    const float* __restrict__ W_c2, const float* __restrict__ b_c2,
    const float* __restrict__ W_n1, const float* __restrict__ b_n1,
    const float* __restrict__ W_n2, const float* __restrict__ b_n2,
    float* __restrict__ out, float* __restrict__ out_coords, int n)
{
    __shared__ _Float16 Act[64 * SA];                       // 16640 B
    __shared__ union {
        unsigned int wt[128 * SW];                          // 33280 B
        struct { float part[2][4][128]; float an[4][128]; } p2;  // 6144 B
    } U;
    __shared__ float agg[4][HDIM];                          // e_sum
    __shared__ float dls[64];
    __shared__ int   nb[64];
    __shared__ int   j0s[4];
    __shared__ float wedge[64];
    __shared__ float wedgep[2][64];

    const int g0  = blockIdx.x * 4;
    const int tid = threadIdx.x;
    const int lane = tid & 63, wid = tid >> 6;
    const int ln31 = lane & 31, grp = lane >> 5;
    const int rt  = wid & 1;            // row-tile (32 edge rows)
    const int ct0 = (wid >> 1) * 2;     // first of two 32-col tiles

    // ---- stage KNN results ----
    if (tid < 64){
        int e = min(g0*KNB + tid, n*KNB - 1);
        nb[tid]  = nidx[e];
        dls[tid] = ndist[e];
    }
    if (tid < 4) j0s[tid] = idx0[min(g0 + tid, n - 1)];
    __syncthreads();

    unsigned int* actd = (unsigned int*)Act;

    // ---- stage Act = [h_self | h_neig] fp16 + WT_e1 ----
    {
        int r = tid >> 2, q = tid & 3, f0 = q * 16;
        const float* hs = h + (size_t)j0s[r >> 4] * FDIM + f0;
        const float* hn = h + (size_t)nb[r] * FDIM + f0;
        unsigned int ds = (unsigned int)(r * SA + f0) >> 1;
        unsigned int dn = (unsigned int)(r * SA + FDIM + f0) >> 1;
        #pragma unroll
        for (int j = 0; j < 8; ++j){
            actd[ds + j] = pack2(hs[2*j], hs[2*j+1]);
            actd[dn + j] = pack2(hn[2*j], hn[2*j+1]);
        }
    }
    {   // WT layer 1
        int nr = tid >> 1, kh = (tid & 1) * 64;
        const uint4* src = (const uint4*)(WTg + nr * 128 + kh);
        unsigned int* dst = U.wt + nr * SW + (tid & 1) * 32;
        #pragma unroll
        for (int j = 0; j < 8; ++j){
            uint4 x = src[j];
            dst[j*4+0]=x.x; dst[j*4+1]=x.y; dst[j*4+2]=x.z; dst[j*4+3]=x.w;
        }
    }
    __syncthreads();

    const unsigned int aBase  = (unsigned int)(rt*32 + ln31) * SW + grp*4;
    const unsigned int bBase0 = (unsigned int)(ct0*32 + ln31) * SW + grp*4;
    const unsigned int bBase1 = (unsigned int)((ct0+1)*32 + ln31) * SW + grp*4;

    auto gemm2 = [&](f32x16& A0, f32x16& A1){
        #pragma unroll
        for (int ks = 0; ks < 8; ++ks){
            const unsigned int off = ks * 8;
            f16x8 af  = ldfrag(actd, aBase + off);
            f16x8 bf0 = ldfrag(U.wt, bBase0 + off);
            f16x8 bf1 = ldfrag(U.wt, bBase1 + off);
            A0 = __builtin_amdgcn_mfma_f32_32x32x16_f16(af, bf0, A0, 0, 0, 0);
            A1 = __builtin_amdgcn_mfma_f32_32x32x16_f16(af, bf1, A1, 0, 0, 0);
        }
    };
    auto stage_wt = [&](const _Float16* Wg){
        int nr = tid >> 1, kh = (tid & 1) * 64;
        const uint4* src = (const uint4*)(Wg + nr * 128 + kh);
        unsigned int* dst = U.wt + nr * SW + (tid & 1) * 32;
        #pragma unroll
        for (int j = 0; j < 8; ++j){
            uint4 x = src[j];
            dst[j*4+0]=x.x; dst[j*4+1]=x.y; dst[j*4+2]=x.z; dst[j*4+3]=x.w;
        }
    };

    // ================= layer e1 (129 -> 128) =================
    {
        float w0a = W_e1[ct0*32 + ln31], w0b = W_e1[(ct0+1)*32 + ln31];
        float bza = b_e1[ct0*32 + ln31], bzb = b_e1[(ct0+1)*32 + ln31];
        f32x16 a0, a1;
        #pragma unroll
        for (int reg = 0; reg < 16; ++reg){
            int row32 = (reg&3) + 8*(reg>>2) + 4*grp;
            float dv = dls[rt*32 + row32];
            a0[reg] = fmaf(dv, w0a, bza);
            a1[reg] = fmaf(dv, w0b, bzb);
        }
        gemm2(a0, a1);
        __syncthreads();     // all reads of Act/WT done
        #pragma unroll
        for (int reg = 0; reg < 16; ++reg){
            int row = rt*32 + (reg&3) + 8*(reg>>2) + 4*grp;
            Act[row*SA + ct0*32 + ln31]     = (_Float16)selu_f(a0[reg]);
            Act[row*SA + (ct0+1)*32 + ln31] = (_Float16)selu_f(a1[reg]);
        }
        stage_wt(WTg + 16384);
        __syncthreads();
    }

    // ================= layer e2 (128 -> 128), e_sum fused =================
    {
        float bza = b_e2[ct0*32 + ln31], bzb = b_e2[(ct0+1)*32 + ln31];
        f32x16 a0, a1;
        #pragma unroll
        for (int reg = 0; reg < 16; ++reg){ a0[reg] = bza; a1[reg] = bzb; }
        gemm2(a0, a1);
        __syncthreads();
        float ev0[16], ev1[16];
        float slo0 = 0.f, shi0 = 0.f, slo1 = 0.f, shi1 = 0.f;
        #pragma unroll
        for (int reg = 0; reg < 16; ++reg){
            ev0[reg] = selu_f(a0[reg]);
            ev1[reg] = selu_f(a1[reg]);
            if (reg < 8){ slo0 += ev0[reg]; slo1 += ev1[reg]; }
            else        { shi0 += ev0[reg]; shi1 += ev1[reg]; }
        }
        slo0 += __shfl_xor(slo0, 32, 64);
        shi0 += __shfl_xor(shi0, 32, 64);
        slo1 += __shfl_xor(slo1, 32, 64);
        shi1 += __shfl_xor(shi1, 32, 64);
        if (grp == 0){
            agg[rt*2+0][ct0*32 + ln31]     = slo0;
            agg[rt*2+1][ct0*32 + ln31]     = shi0;
            agg[rt*2+0][(ct0+1)*32 + ln31] = slo1;
            agg[rt*2+1][(ct0+1)*32 + ln31] = shi1;
        }
        #pragma unroll
        for (int reg = 0; reg < 16; ++reg){
            int row = rt*32 + (reg&3) + 8*(reg>>2) + 4*grp;
            Act[row*SA + ct0*32 + ln31]     = (_Float16)ev0[reg];
            Act[row*SA + (ct0+1)*32 + ln31] = (_Float16)ev1[reg];
        }
        stage_wt(WTg + 2*16384);
        __syncthreads();
    }

    // ================= layer c1 (128 -> 128) + c2 fused =================
    {
        float bza = b_c1[ct0*32 + ln31], bzb = b_c1[(ct0+1)*32 + ln31];
        f32x16 a0, a1;
        #pragma unroll
        for (int reg = 0; reg < 16; ++reg){ a0[reg] = bza; a1[reg] = bzb; }
        gemm2(a0, a1);
        __syncthreads();     // Act & U free after this
        float wca = W_c2[ct0*32 + ln31], wcb = W_c2[(ct0+1)*32 + ln31];
        float p[16];
        #pragma unroll
        for (int reg = 0; reg < 16; ++reg)
            p[reg] = selu_f(a0[reg]) * wca + selu_f(a1[reg]) * wcb;
        #pragma unroll
        for (int msk = 16; msk > 0; msk >>= 1){
            #pragma unroll
            for (int reg = 0; reg < 16; ++reg)
                p[reg] += __shfl_xor(p[reg], msk, 64);
        }
        if (ln31 == 0){
            #pragma unroll
            for (int reg = 0; reg < 16; ++reg){
                int row = rt*32 + (reg&3) + 8*(reg>>2) + 4*grp;
                wedgep[wid>>1][row] = p[reg];
            }
        }
        __syncthreads();
    }

    // ================= epilogue: wedge, coords, node MLP =================
    if (tid < 64) wedge[tid] = b_c2[0] + wedgep[0][tid] + wedgep[1][tid];
    __syncthreads();

    if (tid < 12){
        int nd = tid / 3, c = tid - nd*3;
        int gi = min(g0 + nd, n - 1);
        float ci = coords[3*gi + c];
        float s = 0.f;
        #pragma unroll
        for (int k = 0; k < KNB; ++k){
            int e = nd*KNB + k;
            s += (ci - coords[3*nb[e] + c]) * wedge[e];
        }
        if (g0 + nd < n) out_coords[3*gi + c] = ci + s * (1.0f/KNB);
    }

    int jds[4];
    #pragma unroll
    for (int nd = 0; nd < 4; ++nd) jds[nd] = __builtin_amdgcn_readfirstlane(j0s[nd]);

    {
        int o = tid & 127, half = tid >> 7;
        float a[4] = {0.f, 0.f, 0.f, 0.f};
        if (half == 0){
            for (int in = 0; in < 96; ++in){
                float w = W_n1[in*HDIM + o];
                #pragma unroll
                for (int nd = 0; nd < 4; ++nd) a[nd] = fmaf(agg[nd][in], w, a[nd]);
            }
        } else {
            for (int in = 96; in < 128; ++in){
                float w = W_n1[in*HDIM + o];
                #pragma unroll
                for (int nd = 0; nd < 4; ++nd) a[nd] = fmaf(agg[nd][in], w, a[nd]);
            }
            for (int f = 0; f < 64; ++f){
                float w = W_n1[(128 + f)*HDIM + o];
                #pragma unroll
                for (int nd = 0; nd < 4; ++nd)
                    a[nd] = fmaf(h[(size_t)jds[nd]*FDIM + f], w, a[nd]);
            }
        }
        #pragma unroll
        for (int nd = 0; nd < 4; ++nd) U.p2.part[half][nd][o] = a[nd];
        __syncthreads();
        for (int s = tid; s < 512; s += 256){
            int nd = s >> 7, o2 = s & 127;
            U.p2.an[nd][o2] = selu_f(U.p2.part[0][nd][o2] + U.p2.part[1][nd][o2] + b_n1[o2]);
        }
        __syncthreads();
        float b[4] = {0.f, 0.f, 0.f, 0.f};
        int lo2 = half * 64;
        for (int in = lo2; in < lo2 + 64; ++in){
            float w = W_n2[in*HDIM + o];
            #pragma unroll
            for (int nd = 0; nd < 4; ++nd) b[nd] = fmaf(U.p2.an[nd][in], w, b[nd]);
        }
        __syncthreads();
        #pragma unroll
        for (int nd = 0; nd < 4; ++nd) U.p2.part[half][nd][o] = b[nd];
        __syncthreads();
        for (int s = tid; s < 512; s += 256){
            int nd = s >> 7, o2 = s & 127;
            if (g0 + nd < n)
                out[(size_t)(g0 + nd)*HDIM + o2] =
                    U.p2.part[0][nd][o2] + U.p2.part[1][nd][o2] + b_n2[o2];
        }
    }
}

extern "C" void kernel_launch(void* const* d_in, const int* in_sizes, int n_in,
                              void* d_out, int out_size, void* d_ws, size_t ws_size,
                              hipStream_t stream)
{
    const float* h          = (const float*)d_in[0];
    const float* coords     = (const float*)d_in[1];
    const int*   row_splits = (const int*)  d_in[2];
    const float* W_e1 = (const float*)d_in[3];
    const float* b_e1 = (const float*)d_in[4];
    const float* W_e2 = (const float*)d_in[5];
    const float* b_e2 = (const float*)d_in[6];
    const float* W_c1 = (const float*)d_in[7];
    const float* b_c1 = (const float*)d_in[8];
    const float* W_c2 = (const float*)d_in[9];
    const float* b_c2 = (const float*)d_in[10];
    const float* W_n1 = (const float*)d_in[11];
    const float* b_n1 = (const float*)d_in[12];
    const float* W_n2 = (const float*)d_in[13];
    const float* b_n2 = (const float*)d_in[14];

    const int n    = in_sizes[0] / FDIM;
    const int nseg = in_sizes[2] - 1;

    float* out        = (float*)d_out;
    float* out_coords = out + (size_t)n * HDIM;
    float* out_nidx   = out_coords + (size_t)n * 3;
    float* out_d      = out_nidx + (size_t)n * KNB;

    int*       nidx_i = (int*)d_ws;
    float*     ndist  = (float*)(nidx_i + (size_t)n * KNB);
    int*       idx0   = (int*)(ndist + (size_t)n * KNB);
    _Float16*  WT     = (_Float16*)(idx0 + (size_t)n);   // 3 x 128 x 128 fp16

    conv_kernel<<<192, 256, 0, stream>>>(W_e1, W_e2, W_c1, WT);

    knn_kernel<<<n, 256, 0, stream>>>(coords, row_splits, nseg, n,
                                      nidx_i, ndist, idx0, out_nidx, out_d);

    egcn_node_kernel<<<(n + 3) / 4, 256, 0, stream>>>(
        h, coords, nidx_i, ndist, idx0, WT,
        W_e1, b_e1, b_e2, b_c1, W_c2, b_c2,
        W_n1, b_n1, W_n2, b_n2,
        out, out_coords, n);
}